// Round 6
// baseline (41.156 us; speedup 1.0000x reference)
//
#include <hip/hip_runtime.h>
#include <stdint.h>

#define B_ 32
#define N_ 1024
#define D_ 512
#define G_ 32

typedef __attribute__((ext_vector_type(8))) short short8;
typedef __attribute__((ext_vector_type(4))) float f32x4;
union U4S8 { uint4 u; short8 s; };

// ws float-offsets:
//   [0, 8388608)  : fused-kernel partials, 512 blocks x [32 g][512] f32 = 32 MB
//   WS_DN         : denom partials, 512 x 32
//   WS_WF         : W bf16 frag-layout (2048 uint4 = 32 KB)
#define WS_DN  8388608
#define WS_WF  8404992

__device__ inline uint32_t pack_bf16x2(float a, float b) {
  uint32_t ua = __float_as_uint(a);
  uint32_t ub = __float_as_uint(b);
  ua += 0x7FFFu + ((ua >> 16) & 1u);
  ub += 0x7FFFu + ((ub >> 16) & 1u);
  return (ua >> 16) | (ub & 0xFFFF0000u);
}
__device__ inline uint16_t bf16r(float a) {
  uint32_t u = __float_as_uint(a);
  u += 0x7FFFu + ((u >> 16) & 1u);
  return (uint16_t)(u >> 16);
}

// ---------------- K0: pre-pack W into bf16 MFMA frag layout -----------------
__global__ __launch_bounds__(256) void mdn_k0(
    const float* __restrict__ W, float* ws)
{
  int s = blockIdx.x * 256 + threadIdx.x;     // 0..2047
  int g = s >> 6;
  int d0 = (s & 63) * 8;
  const float4* src = (const float4*)(W + g * D_ + d0);
  float4 f0 = src[0], f1 = src[1];
  int ks = d0 >> 5, ksub = (d0 >> 3) & 3;
  uint4 v;
  v.x = pack_bf16x2(f0.x, f0.y); v.y = pack_bf16x2(f0.z, f0.w);
  v.z = pack_bf16x2(f1.x, f1.y); v.w = pack_bf16x2(f1.z, f1.w);
  ((uint4*)(ws + WS_WF))[(ks * 4 + ksub) * 32 + g] = v;
}

// ---------------- KF: fused logits+softmax+moments --------------------------
// 512 blocks x 256 thr (4 waves), block = (b, 64-row chunk), 2 blocks/CU.
// Phase 1: wave owns 16 rows; x direct-to-reg; MFMA vs prepacked W; in-reg
// softmax; piT -> LDS (stride-68-u32 padded). One barrier.
// Phase 2: moments MFMA. A-frags from LDS piT; B-frags rebuilt from the
// block's own (L2-hot) x rows, mu shared between m1 and m2 frags.
__global__ __launch_bounds__(256, 2) void mdn_kf(
    const float* __restrict__ x, const float* __restrict__ bpi, float* ws)
{
  __shared__ uint32_t SPT[32 * 68];   // 8704 B: piT bf16 [32 g][136 r-slots]
  __shared__ float wpart[4][32];

  const int t = threadIdx.x;
  const int bid = blockIdx.x;
  const int b = bid >> 4;
  const int n0 = (bid & 15) * 64;
  const int w = t >> 6;
  const int lane = t & 63;

  // ---------------- Phase 1: logits ----------------
  const float* abase =
      x + ((size_t)(b * N_ + n0 + w * 16 + (lane & 15))) * D_ + (lane >> 4) * 8;
  const uint4* wf4 = (const uint4*)(ws + WS_WF);

  f32x4 acc0 = {0.f, 0.f, 0.f, 0.f};
  f32x4 acc1 = {0.f, 0.f, 0.f, 0.f};

  #pragma unroll
  for (int h = 0; h < 2; ++h) {
    float4 fa[8], fb[8];
    #pragma unroll
    for (int k = 0; k < 8; ++k) {
      const float* s = abase + (h * 8 + k) * 32;
      fa[k] = *(const float4*)s; fb[k] = *(const float4*)(s + 4);
    }
    #pragma unroll
    for (int k = 0; k < 8; ++k) {
      int ks = h * 8 + k;
      U4S8 a;
      a.u.x = pack_bf16x2(fa[k].x, fa[k].y);
      a.u.y = pack_bf16x2(fa[k].z, fa[k].w);
      a.u.z = pack_bf16x2(fb[k].x, fb[k].y);
      a.u.w = pack_bf16x2(fb[k].z, fb[k].w);
      int wi = (ks * 4 + (lane >> 4)) * 32 + (lane & 15);
      U4S8 w0, w1;
      w0.u = wf4[wi];
      w1.u = wf4[wi + 16];
      acc0 = __builtin_amdgcn_mfma_f32_16x16x32_bf16(a.s, w0.s, acc0, 0, 0, 0);
      acc1 = __builtin_amdgcn_mfma_f32_16x16x32_bf16(a.s, w1.s, acc1, 0, 0, 0);
    }
  }

  // bias + in-register softmax (C layout: g = lane&15 / +16; row =
  // w*16 + (lane>>4)*4 + j; each row lives within a 16-lane group).
  float bs0 = bpi[lane & 15], bs1 = bpi[16 + (lane & 15)];
  float pi0[4], pi1[4];
  float dsum0 = 0.f, dsum1 = 0.f;
  #pragma unroll
  for (int j = 0; j < 4; ++j) {
    float v0 = acc0[j] + bs0, v1 = acc1[j] + bs1;
    float m = fmaxf(v0, v1);
    m = fmaxf(m, __shfl_xor(m, 1));
    m = fmaxf(m, __shfl_xor(m, 2));
    m = fmaxf(m, __shfl_xor(m, 4));
    m = fmaxf(m, __shfl_xor(m, 8));
    float e0 = __expf(v0 - m), e1 = __expf(v1 - m);
    float s = e0 + e1;
    s += __shfl_xor(s, 1); s += __shfl_xor(s, 2);
    s += __shfl_xor(s, 4); s += __shfl_xor(s, 8);
    float inv = 1.0f / s;
    pi0[j] = e0 * inv; pi1[j] = e1 * inv;
    dsum0 += pi0[j];   dsum1 += pi1[j];
  }
  dsum0 += __shfl_xor(dsum0, 16); dsum0 += __shfl_xor(dsum0, 32);
  dsum1 += __shfl_xor(dsum1, 16); dsum1 += __shfl_xor(dsum1, 32);
  if (lane < 16) { wpart[w][lane] = dsum0; wpart[w][16 + lane] = dsum1; }

  // piT -> LDS (u16 writes; row stride 136 bf16 = 68 u32, bank-spread)
  {
    uint16_t* sp16 = (uint16_t*)SPT;
    int rl = w * 16 + (lane >> 4) * 4;
    #pragma unroll
    for (int j = 0; j < 4; ++j) {
      sp16[(lane & 15) * 136 + rl + j] = bf16r(pi0[j]);
      sp16[(16 + (lane & 15)) * 136 + rl + j] = bf16r(pi1[j]);
    }
  }
  __syncthreads();

  if (t < 32) {
    ws[WS_DN + (size_t)bid * 32 + t] =
        wpart[0][t] + wpart[1][t] + wpart[2][t] + wpart[3][t];
  }

  // ---------------- Phase 2: moments ----------------
  // wave w owns cols [w*64, w*64+64) of m1 AND the matching m2 slice.
  f32x4 m1a[2][4] = {{{0.f,0.f,0.f,0.f},{0.f,0.f,0.f,0.f},{0.f,0.f,0.f,0.f},{0.f,0.f,0.f,0.f}},
                     {{0.f,0.f,0.f,0.f},{0.f,0.f,0.f,0.f},{0.f,0.f,0.f,0.f},{0.f,0.f,0.f,0.f}}};
  f32x4 m2a[2][4] = {{{0.f,0.f,0.f,0.f},{0.f,0.f,0.f,0.f},{0.f,0.f,0.f,0.f},{0.f,0.f,0.f,0.f}},
                     {{0.f,0.f,0.f,0.f},{0.f,0.f,0.f,0.f},{0.f,0.f,0.f,0.f},{0.f,0.f,0.f,0.f}}};

  #pragma unroll
  for (int ks = 0; ks < 2; ++ks) {
    U4S8 a0, a1;   // piT A-frags: rows = this wave-k-slice, g = lane&15 (+16)
    a0.u = *(const uint4*)(SPT + (lane & 15) * 68 + ks * 16 + (lane >> 4) * 4);
    a1.u = *(const uint4*)(SPT + (16 + (lane & 15)) * 68 + ks * 16 + (lane >> 4) * 4);
    const float* xp =
        x + ((size_t)(b * N_ + n0 + ks * 32 + (lane >> 4) * 8)) * D_
          + w * 64 + (lane & 15);
    #pragma unroll
    for (int j = 0; j < 4; ++j) {
      float mu[8], sg[8];
      #pragma unroll
      for (int i = 0; i < 8; ++i) {
        mu[i] = xp[i * D_ + j * 16];
        sg[i] = xp[i * D_ + j * 16 + 256];
      }
      U4S8 Bm, B2;
      Bm.u.x = pack_bf16x2(mu[0], mu[1]); Bm.u.y = pack_bf16x2(mu[2], mu[3]);
      Bm.u.z = pack_bf16x2(mu[4], mu[5]); Bm.u.w = pack_bf16x2(mu[6], mu[7]);
      float u0 = fmaf(mu[0], mu[0], sg[0] * sg[0]);
      float u1 = fmaf(mu[1], mu[1], sg[1] * sg[1]);
      float u2 = fmaf(mu[2], mu[2], sg[2] * sg[2]);
      float u3 = fmaf(mu[3], mu[3], sg[3] * sg[3]);
      float u4 = fmaf(mu[4], mu[4], sg[4] * sg[4]);
      float u5 = fmaf(mu[5], mu[5], sg[5] * sg[5]);
      float u6 = fmaf(mu[6], mu[6], sg[6] * sg[6]);
      float u7 = fmaf(mu[7], mu[7], sg[7] * sg[7]);
      B2.u.x = pack_bf16x2(u0, u1); B2.u.y = pack_bf16x2(u2, u3);
      B2.u.z = pack_bf16x2(u4, u5); B2.u.w = pack_bf16x2(u6, u7);
      m1a[0][j] = __builtin_amdgcn_mfma_f32_16x16x32_bf16(a0.s, Bm.s, m1a[0][j], 0, 0, 0);
      m1a[1][j] = __builtin_amdgcn_mfma_f32_16x16x32_bf16(a1.s, Bm.s, m1a[1][j], 0, 0, 0);
      m2a[0][j] = __builtin_amdgcn_mfma_f32_16x16x32_bf16(a0.s, B2.s, m2a[0][j], 0, 0, 0);
      m2a[1][j] = __builtin_amdgcn_mfma_f32_16x16x32_bf16(a1.s, B2.s, m2a[1][j], 0, 0, 0);
    }
  }

  // partial store: P[bid][g][0..256)=m1, [256..512)=m2
  float* P = ws + (size_t)bid * 16384;
  #pragma unroll
  for (int gt = 0; gt < 2; ++gt) {
    #pragma unroll
    for (int j = 0; j < 4; ++j) {
      int col = w * 64 + j * 16 + (lane & 15);
      #pragma unroll
      for (int jj = 0; jj < 4; ++jj) {
        int g = gt * 16 + (lane >> 4) * 4 + jj;
        P[g * 512 + col] = m1a[gt][j][jj];
        P[g * 512 + 256 + col] = m2a[gt][j][jj];
      }
    }
  }
}

// ---------------- K3: reduce 16 row-chunk partials + finalize ---------------
__global__ __launch_bounds__(256) void mdn_k3(
    const float* __restrict__ ws, float* __restrict__ out)
{
  __shared__ float dnm[G_];
  const int blk = blockIdx.x;
  const int b = blk >> 3, oc = blk & 7;   // oc: 32-wide o chunk
  const int t = threadIdx.x;
  if (t < G_) {
    float s = 0.f;
    #pragma unroll
    for (int c = 0; c < 16; ++c) s += ws[WS_DN + (size_t)(b * 16 + c) * 32 + t];
    dnm[t] = s;
    if (oc == 0) out[b * G_ + t] = s * (1.0f / 1024.0f);   // weights
  }
  __syncthreads();
  const int g = t >> 3;
  const int o = oc * 32 + (t & 7) * 4;
  float4 m1 = make_float4(0.f, 0.f, 0.f, 0.f);
  float4 m2 = make_float4(0.f, 0.f, 0.f, 0.f);
  #pragma unroll
  for (int c = 0; c < 16; ++c) {
    const float* p = ws + (size_t)(b * 16 + c) * 16384 + g * 512;
    float4 a = *(const float4*)(p + o);
    float4 c2 = *(const float4*)(p + 256 + o);
    m1.x += a.x; m1.y += a.y; m1.z += a.z; m1.w += a.w;
    m2.x += c2.x; m2.y += c2.y; m2.z += c2.z; m2.w += c2.w;
  }
  float inv = 1.0f / dnm[g];
  float4 lc = make_float4(m1.x * inv, m1.y * inv, m1.z * inv, m1.w * inv);
  float4 sc;
  sc.x = sqrtf(fmaxf(m2.x * inv - lc.x * lc.x, 0.f));
  sc.y = sqrtf(fmaxf(m2.y * inv - lc.y * lc.y, 0.f));
  sc.z = sqrtf(fmaxf(m2.z * inv - lc.z * lc.z, 0.f));
  sc.w = sqrtf(fmaxf(m2.w * inv - lc.w * lc.w, 0.f));
  float* scales = out + 1024;
  float* locs = out + 1024 + 262144;
  int oi = ((b * G_ + g) << 8) + o;
  *(float4*)(scales + oi) = sc;
  *(float4*)(locs + oi) = lc;
}

extern "C" void kernel_launch(void* const* d_in, const int* in_sizes, int n_in,
                              void* d_out, int out_size, void* d_ws, size_t ws_size,
                              hipStream_t stream)
{
  const float* x = (const float*)d_in[0];
  const float* W = (const float*)d_in[1];
  const float* bpi = (const float*)d_in[2];
  float* out = (float*)d_out;
  float* ws = (float*)d_ws;
  hipLaunchKernelGGL(mdn_k0, dim3(8), dim3(256), 0, stream, W, ws);
  hipLaunchKernelGGL(mdn_kf, dim3(512), dim3(256), 0, stream, x, bpi, ws);
  hipLaunchKernelGGL(mdn_k3, dim3(256), dim3(256), 0, stream, ws, out);
}

// Round 7
// 31.470 us; speedup vs baseline: 1.3078x; 1.3078x over previous
//
#include <hip/hip_runtime.h>
#include <stdint.h>

#define B_ 32
#define N_ 1024
#define D_ 512
#define G_ 32

typedef __attribute__((ext_vector_type(8))) short short8;
typedef __attribute__((ext_vector_type(4))) float f32x4;
union U4S8 { uint4 u; short8 s; };

// ws float-offsets:
//   [0, 4194304)   : partials, 256 blocks x [32 g][256 m1 | 256 m2] f32 = 16 MB
//   WS_DN (+8192)  : denom partials, 256 x 32
//   WS_WF (+8192)  : W bf16 frag-layout (2048 uint4 = 32 KB)
#define WS_DN  4194304
#define WS_WF  4202496

__device__ inline uint32_t pack_bf16x2(float a, float b) {
  uint32_t ua = __float_as_uint(a);
  uint32_t ub = __float_as_uint(b);
  ua += 0x7FFFu + ((ua >> 16) & 1u);
  ub += 0x7FFFu + ((ub >> 16) & 1u);
  return (ua >> 16) | (ub & 0xFFFF0000u);
}
__device__ inline uint16_t bf16r(float a) {
  uint32_t u = __float_as_uint(a);
  u += 0x7FFFu + ((u >> 16) & 1u);
  return (uint16_t)(u >> 16);
}
__device__ inline float bflo(uint32_t u) { return __uint_as_float(u << 16); }
__device__ inline float bfhi(uint32_t u) { return __uint_as_float(u & 0xFFFF0000u); }
__device__ inline int slot_of(int o) { return (o & 7) ^ ((o >> 3) & 3); }

// ---------------- K0: pre-pack W into bf16 MFMA frag layout -----------------
__global__ __launch_bounds__(256) void mdn_k0(
    const float* __restrict__ W, float* ws)
{
  int s = blockIdx.x * 256 + threadIdx.x;     // 0..2047
  int g = s >> 6;
  int d0 = (s & 63) * 8;
  const float4* src = (const float4*)(W + g * D_ + d0);
  float4 f0 = src[0], f1 = src[1];
  int ks = d0 >> 5, ksub = (d0 >> 3) & 3;
  uint4 v;
  v.x = pack_bf16x2(f0.x, f0.y); v.y = pack_bf16x2(f0.z, f0.w);
  v.z = pack_bf16x2(f1.x, f1.y); v.w = pack_bf16x2(f1.z, f1.w);
  ((uint4*)(ws + WS_WF))[(ks * 4 + ksub) * 32 + g] = v;
}

// ---------------- KF: single-x-pass fused kernel ----------------------------
// 256 blocks x 512 thr (8 waves x 16 rows = 128 rows), 1 block/CU.
// Phase 1: x direct-to-reg (read ONCE); logits MFMA vs prepacked W; while
//   packing, scatter transposed bf16 copies to LDS: XTmu[o][r], XTsg[o][r]
//   (XOR-swizzled 16B slots). In-register softmax -> piT LDS + denom partials.
// Phase 2: moments MFMA entirely from LDS: A = piT frags, B = mu / (mu^2+sg^2)
//   frags (m2 built in VALU from the bf16 mu/sg frags). Partials -> ws.
__global__ __launch_bounds__(512, 2) void mdn_kf(
    const float* __restrict__ x, const float* __restrict__ bpi, float* ws)
{
  __shared__ uint32_t XTmu[16384];   // 64 KB: [256 o][128 r bf16], swizzled
  __shared__ uint32_t XTsg[16384];   // 64 KB
  __shared__ uint32_t PT[2048];      //  8 KB: piT [32 g][128 r bf16], swizzled
  __shared__ float wpart[8][32];

  const int t = threadIdx.x;
  const int bid = blockIdx.x;
  const int b = bid >> 3;
  const int n0 = (bid & 7) * 128;
  const int w = t >> 6;
  const int lane = t & 63;
  const int l15 = lane & 15, l4 = lane >> 4;

  // ---------------- Phase 1: logits + transposed staging ----------------
  const float* abase =
      x + ((size_t)(b * N_ + n0 + w * 16 + l15)) * D_ + l4 * 8;
  const uint4* wf4 = (const uint4*)(ws + WS_WF);
  const int r = w * 16 + l15;        // this thread's row (0..127)

  f32x4 acc0 = {0.f, 0.f, 0.f, 0.f};
  f32x4 acc1 = {0.f, 0.f, 0.f, 0.f};

  #pragma unroll
  for (int h = 0; h < 2; ++h) {
    float4 fa[8], fb[8];
    #pragma unroll
    for (int k = 0; k < 8; ++k) {
      const float* s = abase + (h * 8 + k) * 32;
      fa[k] = *(const float4*)s; fb[k] = *(const float4*)(s + 4);
    }
    uint16_t* a16 = (uint16_t*)(h ? XTsg : XTmu);
    #pragma unroll
    for (int k = 0; k < 8; ++k) {
      int ks = h * 8 + k;
      uint32_t ua[4];
      ua[0] = pack_bf16x2(fa[k].x, fa[k].y);
      ua[1] = pack_bf16x2(fa[k].z, fa[k].w);
      ua[2] = pack_bf16x2(fb[k].x, fb[k].y);
      ua[3] = pack_bf16x2(fb[k].z, fb[k].w);
      // transposed stage: o = l4*8 + k*32 + (0..7)  (same o for mu and sg arrays)
      int ob = l4 * 8 + k * 32;
      #pragma unroll
      for (int i = 0; i < 4; ++i) {
        int o0 = ob + 2 * i, o1 = o0 + 1;
        a16[o0 * 128 + (r ^ (slot_of(o0) << 3))] = (uint16_t)ua[i];
        a16[o1 * 128 + (r ^ (slot_of(o1) << 3))] = (uint16_t)(ua[i] >> 16);
      }
      // logits MFMA
      U4S8 a; a.u.x = ua[0]; a.u.y = ua[1]; a.u.z = ua[2]; a.u.w = ua[3];
      int wi = (ks * 4 + l4) * 32 + l15;
      U4S8 w0, w1;
      w0.u = wf4[wi];
      w1.u = wf4[wi + 16];
      acc0 = __builtin_amdgcn_mfma_f32_16x16x32_bf16(a.s, w0.s, acc0, 0, 0, 0);
      acc1 = __builtin_amdgcn_mfma_f32_16x16x32_bf16(a.s, w1.s, acc1, 0, 0, 0);
    }
  }

  // bias + in-register softmax (C layout: g = l15 / 16+l15; row = w*16+l4*4+j)
  float bs0 = bpi[l15], bs1 = bpi[16 + l15];
  float pi0[4], pi1[4];
  float dsum0 = 0.f, dsum1 = 0.f;
  #pragma unroll
  for (int j = 0; j < 4; ++j) {
    float v0 = acc0[j] + bs0, v1 = acc1[j] + bs1;
    float m = fmaxf(v0, v1);
    m = fmaxf(m, __shfl_xor(m, 1));
    m = fmaxf(m, __shfl_xor(m, 2));
    m = fmaxf(m, __shfl_xor(m, 4));
    m = fmaxf(m, __shfl_xor(m, 8));
    float e0 = __expf(v0 - m), e1 = __expf(v1 - m);
    float s = e0 + e1;
    s += __shfl_xor(s, 1); s += __shfl_xor(s, 2);
    s += __shfl_xor(s, 4); s += __shfl_xor(s, 8);
    float inv = 1.0f / s;
    pi0[j] = e0 * inv; pi1[j] = e1 * inv;
    dsum0 += pi0[j];   dsum1 += pi1[j];
  }
  dsum0 += __shfl_xor(dsum0, 16); dsum0 += __shfl_xor(dsum0, 32);
  dsum1 += __shfl_xor(dsum1, 16); dsum1 += __shfl_xor(dsum1, 32);
  if (lane < 16) { wpart[w][lane] = dsum0; wpart[w][16 + lane] = dsum1; }

  // piT -> LDS (swizzled, same scheme as XT)
  {
    uint16_t* p16 = (uint16_t*)PT;
    int rbase = w * 16 + l4 * 4;
    int g0 = l15, g1 = 16 + l15;
    int s0 = slot_of(g0) << 3, s1 = slot_of(g1) << 3;
    #pragma unroll
    for (int j = 0; j < 4; ++j) {
      int rr = rbase + j;
      p16[g0 * 128 + (rr ^ s0)] = bf16r(pi0[j]);
      p16[g1 * 128 + (rr ^ s1)] = bf16r(pi1[j]);
    }
  }
  __syncthreads();

  if (t < 32) {
    float s = 0.f;
    #pragma unroll
    for (int ww = 0; ww < 8; ++ww) s += wpart[ww][t];
    ws[WS_DN + (size_t)bid * 32 + t] = s;
  }

  // ---------------- Phase 2: moments from LDS ----------------
  f32x4 m1a[2][2] = {{{0.f,0.f,0.f,0.f},{0.f,0.f,0.f,0.f}},
                     {{0.f,0.f,0.f,0.f},{0.f,0.f,0.f,0.f}}};
  f32x4 m2a[2][2] = {{{0.f,0.f,0.f,0.f},{0.f,0.f,0.f,0.f}},
                     {{0.f,0.f,0.f,0.f},{0.f,0.f,0.f,0.f}}};
  const int gA0 = l15, gA1 = 16 + l15;
  const int sA0 = slot_of(gA0) << 2, sA1 = slot_of(gA1) << 2;

  #pragma unroll
  for (int ks = 0; ks < 4; ++ks) {
    int rofs = ks * 16 + l4 * 4;             // u32 offset within a 256B row
    U4S8 a0, a1;
    a0.u = *(const uint4*)(PT + gA0 * 64 + (rofs ^ sA0));
    a1.u = *(const uint4*)(PT + gA1 * 64 + (rofs ^ sA1));
    #pragma unroll
    for (int ot = 0; ot < 2; ++ot) {
      int o = w * 32 + ot * 16 + l15;
      int idx = o * 64 + (rofs ^ (slot_of(o) << 2));
      U4S8 Bm; Bm.u = *(const uint4*)(XTmu + idx);
      uint4 sg4 = *(const uint4*)(XTsg + idx);
      uint32_t bm[4] = {Bm.u.x, Bm.u.y, Bm.u.z, Bm.u.w};
      uint32_t sw[4] = {sg4.x, sg4.y, sg4.z, sg4.w};
      U4S8 B2;
      uint32_t b2w[4];
      #pragma unroll
      for (int i = 0; i < 4; ++i) {
        float lo = bflo(bm[i]) * bflo(bm[i]) + bflo(sw[i]) * bflo(sw[i]);
        float hi = bfhi(bm[i]) * bfhi(bm[i]) + bfhi(sw[i]) * bfhi(sw[i]);
        b2w[i] = pack_bf16x2(lo, hi);
      }
      B2.u.x = b2w[0]; B2.u.y = b2w[1]; B2.u.z = b2w[2]; B2.u.w = b2w[3];
      m1a[0][ot] = __builtin_amdgcn_mfma_f32_16x16x32_bf16(a0.s, Bm.s, m1a[0][ot], 0, 0, 0);
      m1a[1][ot] = __builtin_amdgcn_mfma_f32_16x16x32_bf16(a1.s, Bm.s, m1a[1][ot], 0, 0, 0);
      m2a[0][ot] = __builtin_amdgcn_mfma_f32_16x16x32_bf16(a0.s, B2.s, m2a[0][ot], 0, 0, 0);
      m2a[1][ot] = __builtin_amdgcn_mfma_f32_16x16x32_bf16(a1.s, B2.s, m2a[1][ot], 0, 0, 0);
    }
  }

  // partial store: [32 g][256 m1 | 256 m2]
  float* dst = ws + (size_t)bid * 16384;
  #pragma unroll
  for (int gt = 0; gt < 2; ++gt) {
    #pragma unroll
    for (int ot = 0; ot < 2; ++ot) {
      int col = w * 32 + ot * 16 + l15;
      #pragma unroll
      for (int jj = 0; jj < 4; ++jj) {
        int g = gt * 16 + l4 * 4 + jj;
        dst[g * 512 + col] = m1a[gt][ot][jj];
        dst[g * 512 + 256 + col] = m2a[gt][ot][jj];
      }
    }
  }
}

// ---------------- K3: reduce 8 row-chunk partials + finalize ----------------
__global__ __launch_bounds__(256) void mdn_k3(
    const float* __restrict__ ws, float* __restrict__ out)
{
  __shared__ float dnm[G_];
  const int blk = blockIdx.x;
  const int b = blk >> 3, oc = blk & 7;   // oc: 32-wide o chunk
  const int t = threadIdx.x;
  if (t < G_) {
    float s = 0.f;
    #pragma unroll
    for (int c = 0; c < 8; ++c) s += ws[WS_DN + (size_t)(b * 8 + c) * 32 + t];
    dnm[t] = s;
    if (oc == 0) out[b * G_ + t] = s * (1.0f / 1024.0f);   // weights
  }
  __syncthreads();
  const int g = t >> 3;
  const int o = oc * 32 + (t & 7) * 4;
  float4 m1 = make_float4(0.f, 0.f, 0.f, 0.f);
  float4 m2 = make_float4(0.f, 0.f, 0.f, 0.f);
  #pragma unroll
  for (int c = 0; c < 8; ++c) {
    const float* p = ws + (size_t)(b * 8 + c) * 16384 + g * 512;
    float4 a = *(const float4*)(p + o);
    float4 c2 = *(const float4*)(p + 256 + o);
    m1.x += a.x; m1.y += a.y; m1.z += a.z; m1.w += a.w;
    m2.x += c2.x; m2.y += c2.y; m2.z += c2.z; m2.w += c2.w;
  }
  float inv = 1.0f / dnm[g];
  float4 lc = make_float4(m1.x * inv, m1.y * inv, m1.z * inv, m1.w * inv);
  float4 sc;
  sc.x = sqrtf(fmaxf(m2.x * inv - lc.x * lc.x, 0.f));
  sc.y = sqrtf(fmaxf(m2.y * inv - lc.y * lc.y, 0.f));
  sc.z = sqrtf(fmaxf(m2.z * inv - lc.z * lc.z, 0.f));
  sc.w = sqrtf(fmaxf(m2.w * inv - lc.w * lc.w, 0.f));
  float* scales = out + 1024;
  float* locs = out + 1024 + 262144;
  int oi = ((b * G_ + g) << 8) + o;
  *(float4*)(scales + oi) = sc;
  *(float4*)(locs + oi) = lc;
}

extern "C" void kernel_launch(void* const* d_in, const int* in_sizes, int n_in,
                              void* d_out, int out_size, void* d_ws, size_t ws_size,
                              hipStream_t stream)
{
  const float* x = (const float*)d_in[0];
  const float* W = (const float*)d_in[1];
  const float* bpi = (const float*)d_in[2];
  float* out = (float*)d_out;
  float* ws = (float*)d_ws;
  hipLaunchKernelGGL(mdn_k0, dim3(8), dim3(256), 0, stream, W, ws);
  hipLaunchKernelGGL(mdn_kf, dim3(256), dim3(512), 0, stream, x, bpi, ws);
  hipLaunchKernelGGL(mdn_k3, dim3(256), dim3(256), 0, stream, ws, out);
}